// Round 7
// baseline (213.175 us; speedup 1.0000x reference)
//
#include <hip/hip_runtime.h>
#include <math.h>
#include <stdint.h>

typedef _Float16 half8 __attribute__((ext_vector_type(8)));
typedef float floatx4 __attribute__((ext_vector_type(4)));

#define NTOK 16384
#define DIM  2048
#define NEXP 64
#define MB   32                    // tokens per block
#define NBLK (NTOK / MB)           // 512 blocks
#define THREADS 512                // 8 waves; wave w owns K-slice [w*256, w*256+256)
#define WSW_H8 16384               // half8 slots per split (64 ksteps x 4 tg x 64 lanes)
#define WSW_BYTES (2 * WSW_H8 * 16)

// ---- prep: split W (fp32) into f16 hi + scaled-lo (2^11), B-fragment order:
// slot(sg,tg,lane) = (sg*4+tg)*64+lane holds W[tg*16+(lane&15)][sg*32+(lane>>4)*8 + 0..7]
__global__ void wprep_kernel(const float* __restrict__ W, _Float16* __restrict__ wsw) {
    const int id   = blockIdx.x * blockDim.x + threadIdx.x; // 0..16383
    const int lane = id & 63;
    const int tg   = (id >> 6) & 3;
    const int sg   = id >> 8;                               // 0..63
    const int e    = tg * 16 + (lane & 15);
    const int k    = sg * 32 + (lane >> 4) * 8;
    const float* src = W + (size_t)e * DIM + k;
    half8 h, l;
#pragma unroll
    for (int j = 0; j < 8; j++) {
        const float v  = src[j];
        const _Float16 hh = (_Float16)v;
        h[j] = hh;
        l[j] = (_Float16)((v - (float)hh) * 2048.0f);
    }
    const size_t slot = (size_t)(sg * 4 + tg) * 64 + lane;
    ((half8*)wsw)[slot]          = h;
    ((half8*)wsw)[WSW_H8 + slot] = l;
}

__device__ __forceinline__ void split_a(const float4& v0, const float4& v1,
                                        half8& hi, half8& lo) {
    const float av[8] = {v0.x, v0.y, v0.z, v0.w, v1.x, v1.y, v1.z, v1.w};
#pragma unroll
    for (int j = 0; j < 8; j++) {
        const _Float16 hh = (_Float16)av[j];
        hi[j] = hh;
        lo[j] = (_Float16)((av[j] - (float)hh) * 2048.0f);
    }
}

template <bool USE_WS>
__global__ __launch_bounds__(THREADS, 2)   // cap VGPR at 256: 2 waves/SIMD
void gating_regB_kernel(const float* __restrict__ x, const float* __restrict__ W,
                        const _Float16* __restrict__ wsw, const float* __restrict__ bias,
                        float* __restrict__ out)
{
    __shared__ __align__(16) float part[8 * MB * 64];   // 64 KB: [wave][tok][exp]

    const int tid  = threadIdx.x;
    const int lane = tid & 63;
    const int w    = tid >> 6;          // 0..7 = K-slice owner
    const int col  = lane & 15;
    const int quad = lane >> 4;
    const int tok0 = blockIdx.x * MB;
    const int sg0  = w * 8;             // first 32-dim k-step of this wave

    floatx4 accm[2][4], accl[2][4];
#pragma unroll
    for (int m = 0; m < 2; m++)
#pragma unroll
        for (int tg = 0; tg < 4; tg++) { accm[m][tg] = {0,0,0,0}; accl[m][tg] = {0,0,0,0}; }

    const half8* bb    = (const half8*)wsw + lane;
    const float* xbase = x + (size_t)tok0 * DIM + quad * 8;

    // ---- K-loop: 4 sub-slices of 64 dims (2 k-steps); B in registers, A from global.
    for (int ss = 0; ss < 4; ++ss) {
        const int sgA = sg0 + 2 * ss;

        // batched loads: 16 B-frag pairs (L2) + 8 A-float4-pairs (HBM stream)
        half8 bh[2][4], bl[2][4];
        if constexpr (USE_WS) {
#pragma unroll
            for (int s2 = 0; s2 < 2; ++s2)
#pragma unroll
                for (int tg = 0; tg < 4; ++tg) {
                    const size_t fi = (size_t)((sgA + s2) * 4 + tg) * 64;
                    bh[s2][tg] = bb[fi];
                    bl[s2][tg] = bb[WSW_H8 + fi];
                }
        } else {
#pragma unroll
            for (int s2 = 0; s2 < 2; ++s2)
#pragma unroll
                for (int tg = 0; tg < 4; ++tg) {
                    const float* wr = W + (size_t)(tg * 16 + col) * DIM + (sgA + s2) * 32 + quad * 8;
                    split_a(*(const float4*)wr, *(const float4*)(wr + 4), bh[s2][tg], bl[s2][tg]);
                }
        }
        float4 av[2][2][2];                        // [m-tile][k-step][j]
#pragma unroll
        for (int m = 0; m < 2; ++m)
#pragma unroll
            for (int s2 = 0; s2 < 2; ++s2) {
                const float* ap = xbase + (size_t)(m * 16 + col) * DIM + (sgA + s2) * 32;
                av[m][s2][0] = *(const float4*)(ap);
                av[m][s2][1] = *(const float4*)(ap + 4);
            }

        __builtin_amdgcn_sched_barrier(0);   // pin: loads above, compute below (no sinking)

#pragma unroll
        for (int m = 0; m < 2; ++m)
#pragma unroll
            for (int s2 = 0; s2 < 2; ++s2) {
                half8 ah, al;
                split_a(av[m][s2][0], av[m][s2][1], ah, al);
#pragma unroll
                for (int tg = 0; tg < 4; ++tg) {
                    accm[m][tg] = __builtin_amdgcn_mfma_f32_16x16x32_f16(ah, bh[s2][tg], accm[m][tg], 0, 0, 0);
                    accl[m][tg] = __builtin_amdgcn_mfma_f32_16x16x32_f16(ah, bl[s2][tg], accl[m][tg], 0, 0, 0);
                    accl[m][tg] = __builtin_amdgcn_mfma_f32_16x16x32_f16(al, bh[s2][tg], accl[m][tg], 0, 0, 0);
                }
            }
    }

    // ---- epilogue: per-wave partials -> LDS  (C/D: row=quad*4+r, col=lane&15)
    const float inv = 1.0f / 2048.0f;
#pragma unroll
    for (int m = 0; m < 2; ++m)
#pragma unroll
        for (int tg = 0; tg < 4; ++tg)
#pragma unroll
            for (int r = 0; r < 4; ++r)
                part[w * 2048 + (m * 16 + quad * 4 + r) * 64 + tg * 16 + col]
                    = accm[m][tg][r] + accl[m][tg][r] * inv;
    __syncthreads();

    // ---- cross-wave K-reduction: thread owns 4 consecutive (tok,exp) pairs
    floatx4 red = {0, 0, 0, 0};
#pragma unroll
    for (int w2 = 0; w2 < 8; ++w2)
        red += *(const floatx4*)(part + w2 * 2048 + tid * 4);
    const floatx4 bv = *(const floatx4*)(bias + ((tid * 4) & 63));
    __syncthreads();                 // all reads done before aliasing fin onto part

    float* fin = part;               // [32 tok][65] stride-65 (conflict-free scan)
#pragma unroll
    for (int i = 0; i < 4; ++i) {
        const int p = tid * 4 + i;
        fin[(p >> 6) * 65 + (p & 63)] = red[i] + bv[i];
    }
    __syncthreads();

    // ---- top-2 + softmax: one thread per token
    if (tid < MB) {
        const int t = tid;
        float v0 = -INFINITY, v1 = -INFINITY;
        int   i0 = 0, i1 = 0;
        for (int e = 0; e < NEXP; e++) {
            const float v = fin[t * 65 + e];
            if (v > v0) { v1 = v0; i1 = i0; v0 = v; i0 = e; }
            else if (v > v1) { v1 = v; i1 = e; }
        }
        const float e1 = expf(v1 - v0);   // v1 <= v0: stable
        const float sden = 1.f + e1;
        const int   g  = tok0 + t;
        out[2 * g + 0] = 1.f / sden;
        out[2 * g + 1] = e1 / sden;
        out[2 * NTOK + 2 * g + 0] = (float)i0;
        out[2 * NTOK + 2 * g + 1] = (float)i1;
    }
}

extern "C" void kernel_launch(void* const* d_in, const int* in_sizes, int n_in,
                              void* d_out, int out_size, void* d_ws, size_t ws_size,
                              hipStream_t stream) {
    const float* x    = (const float*)d_in[0];
    const float* W    = (const float*)d_in[1];
    const float* bias = (const float*)d_in[2];
    float*       out  = (float*)d_out;
    _Float16*    wsw  = (_Float16*)d_ws;

    if (ws_size >= (size_t)WSW_BYTES) {
        hipLaunchKernelGGL(wprep_kernel, dim3(64), dim3(256), 0, stream, (const float*)d_in[1], wsw);
        hipLaunchKernelGGL((gating_regB_kernel<true>), dim3(NBLK), dim3(THREADS), 0, stream,
                           x, W, wsw, bias, out);
    } else {
        hipLaunchKernelGGL((gating_regB_kernel<false>), dim3(NBLK), dim3(THREADS), 0, stream,
                           x, W, wsw, bias, out);
    }
}